// Round 3
// baseline (168.692 us; speedup 1.0000x reference)
//
#include <hip/hip_runtime.h>
#include <hip/hip_bf16.h>
#include <cstdint>

typedef __attribute__((ext_vector_type(8))) short short8;
typedef __attribute__((ext_vector_type(4))) float f32x4;
typedef __attribute__((ext_vector_type(4))) float float4v;
typedef __attribute__((ext_vector_type(4))) unsigned short us4;

#define HD 1024
#define SEQ 2048

// fp32 -> bf16 (round-to-nearest-even), raw bits; inputs are finite.
__device__ __forceinline__ unsigned short f2bf(float f) {
  uint32_t u = __builtin_bit_cast(uint32_t, f);
  return (unsigned short)((u + 0x7FFFu + ((u >> 16) & 1u)) >> 16);
}
__device__ __forceinline__ float bf2f(unsigned short s) {
  return __builtin_bit_cast(float, (uint32_t)s << 16);
}

// async global->LDS, 16B per lane, dest = wave-uniform base + lane*16
__device__ __forceinline__ void gload16(const unsigned short* g, unsigned short* l) {
  __builtin_amdgcn_global_load_lds(
      (const __attribute__((address_space(1))) void*)g,
      (__attribute__((address_space(3))) void*)l, 16, 0, 0);
}

// ---------------- fused prep ----------------
// bx [0,4096):    bf16 cast of inputs (bx<2048) / context
// bx [4096,8192): transpose + bf16 cast of weight (bx-4096)>>10
__global__ __launch_bounds__(256) void prep(
    const float* __restrict__ X, const float* __restrict__ Y,
    const float* __restrict__ w0, const float* __restrict__ w1,
    const float* __restrict__ w2, const float* __restrict__ w3,
    unsigned short* __restrict__ Xh, unsigned short* __restrict__ Yh,
    unsigned short* __restrict__ wt) {
  __shared__ float tile[32][33];
  int bx = blockIdx.x;
  int tid = threadIdx.x;
  if (bx < 4096) {
    const float* src = (bx >= 2048) ? Y : X;
    unsigned short* oh = (bx >= 2048) ? Yh : Xh;
    int i0 = (bx & 2047) * 512 + tid;
#pragma unroll
    for (int r = 0; r < 2; ++r) {
      int i = i0 + r * 256;
      float4v v = ((const float4v*)src)[i];
      us4 h;
#pragma unroll
      for (int j = 0; j < 4; ++j) h[j] = f2bf(v[j]);
      ((us4*)oh)[i] = h;
    }
  } else {
    int t = bx - 4096;
    int z = t >> 10;
    int rem = t & 1023;
    int bxx = rem & 31, byy = rem >> 5;
    const float* in = (z == 0) ? w0 : (z == 1) ? w1 : (z == 2) ? w2 : w3;
    unsigned short* oh = wt + (size_t)z * 1024 * 1024;
    int tx = tid & 31, ty = tid >> 5;
    int x = bxx * 32 + tx;
    int y0 = byy * 32;
    for (int i = ty; i < 32; i += 8)
      tile[i][tx] = in[(size_t)(y0 + i) * HD + x];
    __syncthreads();
    int x2 = y0 + tx;               // k index after transpose
    int y2 = bxx * 32;              // n index after transpose
    for (int i = ty; i < 32; i += 8)
      oh[(size_t)(y2 + i) * HD + x2] = f2bf(tile[tx][i]);
  }
}

// ---------------- batched QKV GEMM, pure bf16, BK=64 ----------------
// z=0: q = inputs@Wq+bq ; z=1: k = context@Wk+bk ; z=2: v = context@Wv+bv.
// 128x128 tile, 256 thr = 4 waves (2m x 2n), wave tile 64x64.
// LDS: 2 planes [128][64], XOR-swizzled 8-chunk rows (slot c of row r holds
// global chunk c ^ ((r>>1)&7)); seg parity folds into two per-lane src ptrs.
__global__ __launch_bounds__(256, 3) void gemm_qkv(
    const unsigned short* __restrict__ Ih, const unsigned short* __restrict__ Ch,
    const unsigned short* __restrict__ wt,
    const float* __restrict__ bq, const float* __restrict__ bk, const float* __restrict__ bv,
    unsigned short* __restrict__ qo, unsigned short* __restrict__ ko,
    unsigned short* __restrict__ vo) {
  __shared__ __align__(16) unsigned short lds[2][128][64];
  const int K = HD, N = HD;
  const size_t P = (size_t)1024 * 1024;
  int z  = blockIdx.z;
  const unsigned short* Ah = z ? Ch : Ih;
  const unsigned short* Bth = wt + (size_t)z * P;
  const float* bias = (z == 0) ? bq : (z == 1) ? bk : bv;
  unsigned short* C = (z == 0) ? qo : (z == 1) ? ko : vo;

  int m0 = blockIdx.x * 128;
  int n0 = blockIdx.y * 128;
  int tid  = threadIdx.x;
  int lane = tid & 63;
  int w    = tid >> 6;            // 0..3
  int quad = lane >> 4;
  int l16  = lane & 15;
  int wm = (w >> 1) * 64;
  int wn = (w & 1) * 64;

  int ro = lane >> 3;             // 0..7 row-in-seg
  int sl = lane & 7;              // slot
  int ge = sl ^ (ro >> 1);        // even-seg global chunk
  int go = ge ^ 4;                // odd-seg
  const unsigned short* spA_e = Ah  + (size_t)(m0 + ro) * K + ge * 8;
  const unsigned short* spA_o = Ah  + (size_t)(m0 + ro) * K + go * 8;
  const unsigned short* spB_e = Bth + (size_t)(n0 + ro) * K + ge * 8;
  const unsigned short* spB_o = Bth + (size_t)(n0 + ro) * K + go * 8;

  f32x4 acc[4][4];
#pragma unroll
  for (int t = 0; t < 4; ++t)
#pragma unroll
    for (int u = 0; u < 4; ++u) acc[t][u] = (f32x4){0.f, 0.f, 0.f, 0.f};

  for (int k0 = 0; k0 < K; k0 += 64) {
    __syncthreads();
#pragma unroll
    for (int i = 0; i < 4; ++i) {
      int seg = w + i * 4;
      const unsigned short* pa = (seg & 1) ? spA_o : spA_e;
      const unsigned short* pb = (seg & 1) ? spB_o : spB_e;
      gload16(pa + (size_t)seg * 8 * K + k0, &lds[0][seg * 8][0]);
      gload16(pb + (size_t)seg * 8 * K + k0, &lds[1][seg * 8][0]);
    }
    __syncthreads();

#pragma unroll
    for (int j = 0; j < 2; ++j) {
      int sl8 = (((j << 2) | quad) ^ (l16 >> 1)) * 8;
      short8 ah[4], bh[4];
#pragma unroll
      for (int t = 0; t < 4; ++t)
        ah[t] = *(const short8*)&lds[0][wm + t * 16 + l16][sl8];
#pragma unroll
      for (int u = 0; u < 4; ++u)
        bh[u] = *(const short8*)&lds[1][wn + u * 16 + l16][sl8];
#pragma unroll
      for (int t = 0; t < 4; ++t)
#pragma unroll
        for (int u = 0; u < 4; ++u)
          acc[t][u] = __builtin_amdgcn_mfma_f32_16x16x32_bf16(ah[t], bh[u], acc[t][u], 0, 0, 0);
    }
  }

#pragma unroll
  for (int t = 0; t < 4; ++t) {
    int row = m0 + wm + t * 16 + quad * 4;
#pragma unroll
    for (int u = 0; u < 4; ++u) {
      int col = n0 + wn + u * 16 + l16;
      float bvv = bias[col];
#pragma unroll
      for (int i = 0; i < 4; ++i)
        C[(size_t)(row + i) * N + col] = f2bf(acc[t][u][i] + bvv);
    }
  }
}

// ---------------- O GEMM: structural clone of gemm_qkv ----------------
// 128x128 tile, 256 thr = 4 waves (2m x 2n), wave tile 64x64, acc 4x4.
// grid (32,8) = 256 blocks (1/CU, tail-free). fp32 output + bias, direct write.
// Same XOR-swizzled LDS + gload16 staging as gemm_qkv; MFMA:ds_read ratio 16:8
// per j-step vs the old 128x64 kernel's 8:6, and ~33% less staged bytes/CU.
__global__ __launch_bounds__(256, 3) void gemm_o(
    const unsigned short* __restrict__ Ah, const unsigned short* __restrict__ Bth,
    const float* __restrict__ bias, float* __restrict__ C) {
  __shared__ __align__(16) unsigned short lds[2][128][64];
  const int K = HD, N = HD;
  int m0 = blockIdx.x * 128;
  int n0 = blockIdx.y * 128;
  int tid  = threadIdx.x;
  int lane = tid & 63;
  int w    = tid >> 6;            // 0..3
  int quad = lane >> 4;
  int l16  = lane & 15;
  int wm = (w >> 1) * 64;
  int wn = (w & 1) * 64;

  int ro = lane >> 3;             // 0..7 row-in-seg
  int sl = lane & 7;              // slot
  int ge = sl ^ (ro >> 1);        // even-seg global chunk
  int go = ge ^ 4;                // odd-seg
  const unsigned short* spA_e = Ah  + (size_t)(m0 + ro) * K + ge * 8;
  const unsigned short* spA_o = Ah  + (size_t)(m0 + ro) * K + go * 8;
  const unsigned short* spB_e = Bth + (size_t)(n0 + ro) * K + ge * 8;
  const unsigned short* spB_o = Bth + (size_t)(n0 + ro) * K + go * 8;

  f32x4 acc[4][4];
#pragma unroll
  for (int t = 0; t < 4; ++t)
#pragma unroll
    for (int u = 0; u < 4; ++u) acc[t][u] = (f32x4){0.f, 0.f, 0.f, 0.f};

  for (int k0 = 0; k0 < K; k0 += 64) {
    __syncthreads();
#pragma unroll
    for (int i = 0; i < 4; ++i) {
      int seg = w + i * 4;
      const unsigned short* pa = (seg & 1) ? spA_o : spA_e;
      const unsigned short* pb = (seg & 1) ? spB_o : spB_e;
      gload16(pa + (size_t)seg * 8 * K + k0, &lds[0][seg * 8][0]);
      gload16(pb + (size_t)seg * 8 * K + k0, &lds[1][seg * 8][0]);
    }
    __syncthreads();

#pragma unroll
    for (int j = 0; j < 2; ++j) {
      int sl8 = (((j << 2) | quad) ^ (l16 >> 1)) * 8;
      short8 ah[4], bh[4];
#pragma unroll
      for (int t = 0; t < 4; ++t)
        ah[t] = *(const short8*)&lds[0][wm + t * 16 + l16][sl8];
#pragma unroll
      for (int u = 0; u < 4; ++u)
        bh[u] = *(const short8*)&lds[1][wn + u * 16 + l16][sl8];
#pragma unroll
      for (int t = 0; t < 4; ++t)
#pragma unroll
        for (int u = 0; u < 4; ++u)
          acc[t][u] = __builtin_amdgcn_mfma_f32_16x16x32_bf16(ah[t], bh[u], acc[t][u], 0, 0, 0);
    }
  }

#pragma unroll
  for (int t = 0; t < 4; ++t) {
    int row = m0 + wm + t * 16 + quad * 4;
#pragma unroll
    for (int u = 0; u < 4; ++u) {
      int col = n0 + wn + u * 16 + l16;
      float bvv = bias[col];
#pragma unroll
      for (int i = 0; i < 4; ++i)
        C[(size_t)(row + i) * N + col] = acc[t][u][i] + bvv;
    }
  }
}

// ---------------- fused RoPE + per-(b,s) head-attention, MFMA version --------
// One wave per position m = b*S+s; no __syncthreads.
__global__ __launch_bounds__(256) void attn_rope_k(
    const unsigned short* __restrict__ q, const unsigned short* __restrict__ kk,
    const unsigned short* __restrict__ v,
    float* __restrict__ attn_out, unsigned short* __restrict__ ctx_h) {
  __shared__ __align__(16) unsigned short vs[4][16][64];
  int tid = threadIdx.x;
  int lane = tid & 63;
  int w = tid >> 6;               // wave id 0..3
  int m = blockIdx.x * 4 + w;     // position b*S + s
  int s = m & (SEQ - 1);
  int b = m >> 11;
  int l16 = lane & 15;
  int quad = lane >> 4;

  // ---- stage V (this wave's slice) into LDS, async ----
  {
    unsigned short* dst = &vs[w][0][0];
    const unsigned short* src = v + (size_t)m * HD;
    gload16(src + lane * 8, dst);
    gload16(src + 512 + lane * 8, dst + 512);
  }

  // ---- load Q,K fragments (f32 working copies) ----
  const unsigned short* qrow = q + (size_t)m * HD + l16 * 64 + quad * 8;
  const unsigned short* krow = kk + (size_t)m * HD + l16 * 64 + quad * 8;
  float qf[2][8], kf[2][8];
#pragma unroll
  for (int j = 0; j < 2; ++j) {
    short8 qv = *(const short8*)(qrow + j * 32);
    short8 kv = *(const short8*)(krow + j * 32);
#pragma unroll
    for (int e = 0; e < 8; ++e) {
      qf[j][e] = bf2f((unsigned short)qv[e]);
      kf[j][e] = bf2f((unsigned short)kv[e]);
    }
  }

  // ---- RoPE in-register ----
  const float C = 0.025952563241307517f;        // log2(10000)/512
  const float I2PI = 0.15915494309189535f;
  float fs = (float)s;
  int pbase = (l16 & 7) * 64 + quad * 8;
  bool hi = (l16 & 8) != 0;
#pragma unroll
  for (int j = 0; j < 2; ++j) {
#pragma unroll
    for (int e = 0; e < 8; ++e) {
      int p = pbase + j * 32 + e;
      float f = exp2f(-(float)p * C);
      float rev = fs * f * I2PI;
      rev -= floorf(rev);
      float sv = __builtin_amdgcn_sinf(rev);
      float cv = __builtin_amdgcn_cosf(rev);
      float pq = __shfl_xor(qf[j][e], 8);
      float pk = __shfl_xor(kf[j][e], 8);
      float sg = hi ? sv : -sv;
      qf[j][e] = qf[j][e] * cv + pq * sg;
      kf[j][e] = kf[j][e] * cv + pk * sg;
    }
  }

  // ---- pack to bf16 fragments ----
  short8 qh[2], kh[2];
#pragma unroll
  for (int j = 0; j < 2; ++j)
#pragma unroll
    for (int e = 0; e < 8; ++e) {
      qh[j][e] = (short)f2bf(qf[j][e]);
      kh[j][e] = (short)f2bf(kf[j][e]);
    }

  // ---- S' = K * Q^T : lane holds S'[t=quad*4+i][h=l16] ----
  f32x4 acc = (f32x4){0.f, 0.f, 0.f, 0.f};
  acc = __builtin_amdgcn_mfma_f32_16x16x32_bf16(kh[0], qh[0], acc, 0, 0, 0);
  acc = __builtin_amdgcn_mfma_f32_16x16x32_bf16(kh[1], qh[1], acc, 0, 0, 0);

  // ---- softmax over t (4 in-lane + cross-quad) ----
  float sc[4];
#pragma unroll
  for (int i = 0; i < 4; ++i) sc[i] = acc[i] * 0.125f;   // 1/sqrt(64)
  float mx = fmaxf(fmaxf(sc[0], sc[1]), fmaxf(sc[2], sc[3]));
  mx = fmaxf(mx, __shfl_xor(mx, 16));
  mx = fmaxf(mx, __shfl_xor(mx, 32));
  float ee[4];
  float sum = 0.f;
#pragma unroll
  for (int i = 0; i < 4; ++i) { ee[i] = expf(sc[i] - mx); sum += ee[i]; }
  sum += __shfl_xor(sum, 16);
  sum += __shfl_xor(sum, 32);
  float inv = 1.0f / sum;
  f32x4 av;
#pragma unroll
  for (int i = 0; i < 4; ++i) av[i] = ee[i] * inv;

  // ---- attn store: attn[m, h=l16, t=quad*4+i], one f32x4 per lane ----
  *(f32x4*)(attn_out + (size_t)m * 256 + l16 * 16 + quad * 4) = av;

  // ---- gather full attn row a[h=l16][t] via shfl ----
  float sh[4][4];
#pragma unroll
  for (int i = 0; i < 4; ++i) {
    sh[0][i] = av[i];
    sh[1][i] = __shfl_xor(av[i], 16);
    sh[2][i] = __shfl_xor(av[i], 32);
    sh[3][i] = __shfl_xor(sh[1][i], 32);
  }

  // ---- PV: ctx[h=l16][d = quad*16 + 0..15] ----
  asm volatile("s_waitcnt vmcnt(0)" ::: "memory");
  float c[16];
#pragma unroll
  for (int d = 0; d < 16; ++d) c[d] = 0.f;
  const unsigned short(*vw)[64] = vs[w];
  int d0 = quad * 16;
#pragma unroll
  for (int qq = 0; qq < 4; ++qq) {
    int tb = ((quad ^ qq) << 2);
#pragma unroll
    for (int i = 0; i < 4; ++i) {
      int t = tb + i;
      float aval = sh[qq][i];
      short8 v0 = *(const short8*)&vw[t][d0];
      short8 v1 = *(const short8*)&vw[t][d0 + 8];
#pragma unroll
      for (int d = 0; d < 8; ++d) {
        c[d]     = fmaf(aval, bf2f((unsigned short)v0[d]), c[d]);
        c[8 + d] = fmaf(aval, bf2f((unsigned short)v1[d]), c[8 + d]);
      }
    }
  }

  // ---- ctx store in transpose(0,2,1,3)-scrambled layout, 2x short8/lane ----
  int row = b * SEQ + l16 * 128 + (s >> 4);
  int col = (s & 15) * 64 + d0;
  unsigned short* cp = ctx_h + (size_t)row * HD + col;
  short8 o0, o1;
#pragma unroll
  for (int d = 0; d < 8; ++d) {
    o0[d] = (short)f2bf(c[d]);
    o1[d] = (short)f2bf(c[8 + d]);
  }
  *(short8*)cp = o0;
  *((short8*)(cp + 8)) = o1;
}

extern "C" void kernel_launch(void* const* d_in, const int* in_sizes, int n_in,
                              void* d_out, int out_size, void* d_ws, size_t ws_size,
                              hipStream_t stream) {
  const float* inputs  = (const float*)d_in[0];
  const float* context = (const float*)d_in[1];
  const float* Wq = (const float*)d_in[2];
  const float* bq = (const float*)d_in[3];
  const float* Wk = (const float*)d_in[4];
  const float* bk = (const float*)d_in[5];
  const float* Wv = (const float*)d_in[6];
  const float* bv = (const float*)d_in[7];
  const float* Wo = (const float*)d_in[8];
  const float* bo = (const float*)d_in[9];

  float* out  = (float*)d_out;                     // [2,2048,1024] flat
  float* attn = out + (size_t)4096 * 1024;         // [2,2048,16,16] flat

  // ws layout (MB offsets): q=0, k=8, v=16, wt=24..32, Ih=32..40, Ch=40..48.
  // ctxh aliases Ih (dead after gemm_qkv; cross-dispatch only).
  const size_t MB = 1ull << 20;
  char* wsb = (char*)d_ws;
  unsigned short* q  = (unsigned short*)(wsb + 0 * MB);
  unsigned short* k  = (unsigned short*)(wsb + 8 * MB);
  unsigned short* v  = (unsigned short*)(wsb + 16 * MB);
  unsigned short* wt = (unsigned short*)(wsb + 24 * MB);
  unsigned short* Ih = (unsigned short*)(wsb + 32 * MB);
  unsigned short* Ch = (unsigned short*)(wsb + 40 * MB);
  unsigned short* ctxh = Ih;   // alias, cross-dispatch only

  prep<<<8192, 256, 0, stream>>>(inputs, context, Wq, Wk, Wv, Wo, Ih, Ch, wt);

  gemm_qkv<<<dim3(32, 8, 3), 256, 0, stream>>>(Ih, Ch, wt, bq, bk, bv, q, k, v);

  attn_rope_k<<<1024, 256, 0, stream>>>(q, k, v, attn, ctxh);

  const size_t P = (size_t)1024 * 1024;
  gemm_o<<<dim3(32, 8), 256, 0, stream>>>(ctxh, wt + 3 * P, bo, out);
}

// Round 4
// 161.269 us; speedup vs baseline: 1.0460x; 1.0460x over previous
//
#include <hip/hip_runtime.h>
#include <hip/hip_bf16.h>
#include <cstdint>

typedef __attribute__((ext_vector_type(8))) short short8;
typedef __attribute__((ext_vector_type(4))) float f32x4;
typedef __attribute__((ext_vector_type(4))) float float4v;
typedef __attribute__((ext_vector_type(4))) unsigned short us4;

#define HD 1024
#define SEQ 2048

// fp32 -> bf16 (round-to-nearest-even), raw bits; inputs are finite.
__device__ __forceinline__ unsigned short f2bf(float f) {
  uint32_t u = __builtin_bit_cast(uint32_t, f);
  return (unsigned short)((u + 0x7FFFu + ((u >> 16) & 1u)) >> 16);
}
__device__ __forceinline__ float bf2f(unsigned short s) {
  return __builtin_bit_cast(float, (uint32_t)s << 16);
}

// async global->LDS, 16B per lane, dest = wave-uniform base + lane*16
__device__ __forceinline__ void gload16(const unsigned short* g, unsigned short* l) {
  __builtin_amdgcn_global_load_lds(
      (const __attribute__((address_space(1))) void*)g,
      (__attribute__((address_space(3))) void*)l, 16, 0, 0);
}

// ---------------- fused prep ----------------
// bx [0,4096):    bf16 cast of inputs (bx<2048) / context
// bx [4096,8192): transpose + bf16 cast of weight (bx-4096)>>10
__global__ __launch_bounds__(256) void prep(
    const float* __restrict__ X, const float* __restrict__ Y,
    const float* __restrict__ w0, const float* __restrict__ w1,
    const float* __restrict__ w2, const float* __restrict__ w3,
    unsigned short* __restrict__ Xh, unsigned short* __restrict__ Yh,
    unsigned short* __restrict__ wt) {
  __shared__ float tile[32][33];
  int bx = blockIdx.x;
  int tid = threadIdx.x;
  if (bx < 4096) {
    const float* src = (bx >= 2048) ? Y : X;
    unsigned short* oh = (bx >= 2048) ? Yh : Xh;
    int i0 = (bx & 2047) * 512 + tid;
#pragma unroll
    for (int r = 0; r < 2; ++r) {
      int i = i0 + r * 256;
      float4v v = ((const float4v*)src)[i];
      us4 h;
#pragma unroll
      for (int j = 0; j < 4; ++j) h[j] = f2bf(v[j]);
      ((us4*)oh)[i] = h;
    }
  } else {
    int t = bx - 4096;
    int z = t >> 10;
    int rem = t & 1023;
    int bxx = rem & 31, byy = rem >> 5;
    const float* in = (z == 0) ? w0 : (z == 1) ? w1 : (z == 2) ? w2 : w3;
    unsigned short* oh = wt + (size_t)z * 1024 * 1024;
    int tx = tid & 31, ty = tid >> 5;
    int x = bxx * 32 + tx;
    int y0 = byy * 32;
    for (int i = ty; i < 32; i += 8)
      tile[i][tx] = in[(size_t)(y0 + i) * HD + x];
    __syncthreads();
    int x2 = y0 + tx;               // k index after transpose
    int y2 = bxx * 32;              // n index after transpose
    for (int i = ty; i < 32; i += 8)
      oh[(size_t)(y2 + i) * HD + x2] = f2bf(tile[tx][i]);
  }
}

// ---------------- batched QKV GEMM, pure bf16, BK=64 ----------------
// z=0: q = inputs@Wq+bq ; z=1: k = context@Wk+bk ; z=2: v = context@Wv+bv.
// 128x128 tile, 256 thr = 4 waves (2m x 2n), wave tile 64x64.
// LDS: 2 planes [128][64], XOR-swizzled 8-chunk rows (slot c of row r holds
// global chunk c ^ ((r>>1)&7)); seg parity folds into two per-lane src ptrs.
// XCD swizzle: block->XCD is x%8 here (32*y, 256*z both ==0 mod 8), so
// sx=(x&7)*4+(x>>3) pins a contiguous 512-row A-chunk (1MB) per XCD L2.
__global__ __launch_bounds__(256, 3) void gemm_qkv(
    const unsigned short* __restrict__ Ih, const unsigned short* __restrict__ Ch,
    const unsigned short* __restrict__ wt,
    const float* __restrict__ bq, const float* __restrict__ bk, const float* __restrict__ bv,
    unsigned short* __restrict__ qo, unsigned short* __restrict__ ko,
    unsigned short* __restrict__ vo) {
  __shared__ __align__(16) unsigned short lds[2][128][64];
  const int K = HD, N = HD;
  const size_t P = (size_t)1024 * 1024;
  int z  = blockIdx.z;
  const unsigned short* Ah = z ? Ch : Ih;
  const unsigned short* Bth = wt + (size_t)z * P;
  const float* bias = (z == 0) ? bq : (z == 1) ? bk : bv;
  unsigned short* C = (z == 0) ? qo : (z == 1) ? ko : vo;

  int bx = blockIdx.x;
  int sx = ((bx & 7) << 2) | (bx >> 3);   // XCD-contiguous m-chunks
  int m0 = sx * 128;
  int n0 = blockIdx.y * 128;
  int tid  = threadIdx.x;
  int lane = tid & 63;
  int w    = tid >> 6;            // 0..3
  int quad = lane >> 4;
  int l16  = lane & 15;
  int wm = (w >> 1) * 64;
  int wn = (w & 1) * 64;

  int ro = lane >> 3;             // 0..7 row-in-seg
  int sl = lane & 7;              // slot
  int ge = sl ^ (ro >> 1);        // even-seg global chunk
  int go = ge ^ 4;                // odd-seg
  const unsigned short* spA_e = Ah  + (size_t)(m0 + ro) * K + ge * 8;
  const unsigned short* spA_o = Ah  + (size_t)(m0 + ro) * K + go * 8;
  const unsigned short* spB_e = Bth + (size_t)(n0 + ro) * K + ge * 8;
  const unsigned short* spB_o = Bth + (size_t)(n0 + ro) * K + go * 8;

  f32x4 acc[4][4];
#pragma unroll
  for (int t = 0; t < 4; ++t)
#pragma unroll
    for (int u = 0; u < 4; ++u) acc[t][u] = (f32x4){0.f, 0.f, 0.f, 0.f};

  for (int k0 = 0; k0 < K; k0 += 64) {
    __syncthreads();
#pragma unroll
    for (int i = 0; i < 4; ++i) {
      int seg = w + i * 4;
      const unsigned short* pa = (seg & 1) ? spA_o : spA_e;
      const unsigned short* pb = (seg & 1) ? spB_o : spB_e;
      gload16(pa + (size_t)seg * 8 * K + k0, &lds[0][seg * 8][0]);
      gload16(pb + (size_t)seg * 8 * K + k0, &lds[1][seg * 8][0]);
    }
    __syncthreads();

#pragma unroll
    for (int j = 0; j < 2; ++j) {
      int sl8 = (((j << 2) | quad) ^ (l16 >> 1)) * 8;
      short8 ah[4], bh[4];
#pragma unroll
      for (int t = 0; t < 4; ++t)
        ah[t] = *(const short8*)&lds[0][wm + t * 16 + l16][sl8];
#pragma unroll
      for (int u = 0; u < 4; ++u)
        bh[u] = *(const short8*)&lds[1][wn + u * 16 + l16][sl8];
#pragma unroll
      for (int t = 0; t < 4; ++t)
#pragma unroll
        for (int u = 0; u < 4; ++u)
          acc[t][u] = __builtin_amdgcn_mfma_f32_16x16x32_bf16(ah[t], bh[u], acc[t][u], 0, 0, 0);
    }
  }

#pragma unroll
  for (int t = 0; t < 4; ++t) {
    int row = m0 + wm + t * 16 + quad * 4;
#pragma unroll
    for (int u = 0; u < 4; ++u) {
      int col = n0 + wn + u * 16 + l16;
      float bvv = bias[col];
#pragma unroll
      for (int i = 0; i < 4; ++i)
        C[(size_t)(row + i) * N + col] = f2bf(acc[t][u][i] + bvv);
    }
  }
}

// ---------------- O GEMM, pure bf16, 128x64 tile, direct write ----------------
// grid (32,16) = 512 blocks (2/CU). Full K per block -> no atomics, no zero-fill.
// 4 waves (2m x 2n), wave tile 64x32 (4x2 accs). LDS A[128][64] + B[64][64].
// Same XCD x-swizzle as gemm_qkv (32*y == 0 mod 8 -> XCD = x%8).
__global__ __launch_bounds__(256, 3) void gemm_o(
    const unsigned short* __restrict__ Ah, const unsigned short* __restrict__ Bth,
    const float* __restrict__ bias, float* __restrict__ C) {
  __shared__ __align__(16) unsigned short ldsA[128][64];
  __shared__ __align__(16) unsigned short ldsB[64][64];
  const int K = HD, N = HD;
  int bx = blockIdx.x;
  int sx = ((bx & 7) << 2) | (bx >> 3);
  int m0 = sx * 128;
  int n0 = blockIdx.y * 64;
  int tid  = threadIdx.x;
  int lane = tid & 63;
  int w    = tid >> 6;            // 0..3
  int quad = lane >> 4;
  int l16  = lane & 15;
  int wm = (w >> 1) * 64;         // 0/64
  int wn = (w & 1) * 32;          // 0/32

  int ro = lane >> 3;
  int sl = lane & 7;
  int ge = sl ^ (ro >> 1);
  int go = ge ^ 4;
  const unsigned short* spA_e = Ah  + (size_t)(m0 + ro) * K + ge * 8;
  const unsigned short* spA_o = Ah  + (size_t)(m0 + ro) * K + go * 8;
  const unsigned short* spB_e = Bth + (size_t)(n0 + ro) * K + ge * 8;
  const unsigned short* spB_o = Bth + (size_t)(n0 + ro) * K + go * 8;

  f32x4 acc[4][2];
#pragma unroll
  for (int t = 0; t < 4; ++t)
#pragma unroll
    for (int u = 0; u < 2; ++u) acc[t][u] = (f32x4){0.f, 0.f, 0.f, 0.f};

  for (int k0 = 0; k0 < K; k0 += 64) {
    __syncthreads();
#pragma unroll
    for (int i = 0; i < 4; ++i) {          // A segs: w, w+4, w+8, w+12
      int seg = w + i * 4;
      const unsigned short* pa = (seg & 1) ? spA_o : spA_e;
      gload16(pa + (size_t)seg * 8 * K + k0, &ldsA[seg * 8][0]);
    }
#pragma unroll
    for (int i = 0; i < 2; ++i) {          // B segs: w, w+4
      int seg = w + i * 4;
      const unsigned short* pb = (seg & 1) ? spB_o : spB_e;
      gload16(pb + (size_t)seg * 8 * K + k0, &ldsB[seg * 8][0]);
    }
    __syncthreads();

#pragma unroll
    for (int j = 0; j < 2; ++j) {
      int sl8 = (((j << 2) | quad) ^ (l16 >> 1)) * 8;
      short8 ah[4], bh[2];
#pragma unroll
      for (int t = 0; t < 4; ++t)
        ah[t] = *(const short8*)&ldsA[wm + t * 16 + l16][sl8];
#pragma unroll
      for (int u = 0; u < 2; ++u)
        bh[u] = *(const short8*)&ldsB[wn + u * 16 + l16][sl8];
#pragma unroll
      for (int t = 0; t < 4; ++t)
#pragma unroll
        for (int u = 0; u < 2; ++u)
          acc[t][u] = __builtin_amdgcn_mfma_f32_16x16x32_bf16(ah[t], bh[u], acc[t][u], 0, 0, 0);
    }
  }

#pragma unroll
  for (int t = 0; t < 4; ++t) {
    int row = m0 + wm + t * 16 + quad * 4;
#pragma unroll
    for (int u = 0; u < 2; ++u) {
      int col = n0 + wn + u * 16 + l16;
      float bvv = bias[col];
#pragma unroll
      for (int i = 0; i < 4; ++i)
        C[(size_t)(row + i) * N + col] = acc[t][u][i] + bvv;
    }
  }
}

// ---------------- fused RoPE + per-(b,s) head-attention, MFMA version --------
// One wave per position m = b*S+s; no __syncthreads.
__global__ __launch_bounds__(256) void attn_rope_k(
    const unsigned short* __restrict__ q, const unsigned short* __restrict__ kk,
    const unsigned short* __restrict__ v,
    float* __restrict__ attn_out, unsigned short* __restrict__ ctx_h) {
  __shared__ __align__(16) unsigned short vs[4][16][64];
  int tid = threadIdx.x;
  int lane = tid & 63;
  int w = tid >> 6;               // wave id 0..3
  int m = blockIdx.x * 4 + w;     // position b*S + s
  int s = m & (SEQ - 1);
  int b = m >> 11;
  int l16 = lane & 15;
  int quad = lane >> 4;

  // ---- stage V (this wave's slice) into LDS, async ----
  {
    unsigned short* dst = &vs[w][0][0];
    const unsigned short* src = v + (size_t)m * HD;
    gload16(src + lane * 8, dst);
    gload16(src + 512 + lane * 8, dst + 512);
  }

  // ---- load Q,K fragments (f32 working copies) ----
  const unsigned short* qrow = q + (size_t)m * HD + l16 * 64 + quad * 8;
  const unsigned short* krow = kk + (size_t)m * HD + l16 * 64 + quad * 8;
  float qf[2][8], kf[2][8];
#pragma unroll
  for (int j = 0; j < 2; ++j) {
    short8 qv = *(const short8*)(qrow + j * 32);
    short8 kv = *(const short8*)(krow + j * 32);
#pragma unroll
    for (int e = 0; e < 8; ++e) {
      qf[j][e] = bf2f((unsigned short)qv[e]);
      kf[j][e] = bf2f((unsigned short)kv[e]);
    }
  }

  // ---- RoPE in-register ----
  const float C = 0.025952563241307517f;        // log2(10000)/512
  const float I2PI = 0.15915494309189535f;
  float fs = (float)s;
  int pbase = (l16 & 7) * 64 + quad * 8;
  bool hi = (l16 & 8) != 0;
#pragma unroll
  for (int j = 0; j < 2; ++j) {
#pragma unroll
    for (int e = 0; e < 8; ++e) {
      int p = pbase + j * 32 + e;
      float f = exp2f(-(float)p * C);
      float rev = fs * f * I2PI;
      rev -= floorf(rev);
      float sv = __builtin_amdgcn_sinf(rev);
      float cv = __builtin_amdgcn_cosf(rev);
      float pq = __shfl_xor(qf[j][e], 8);
      float pk = __shfl_xor(kf[j][e], 8);
      float sg = hi ? sv : -sv;
      qf[j][e] = qf[j][e] * cv + pq * sg;
      kf[j][e] = kf[j][e] * cv + pk * sg;
    }
  }

  // ---- pack to bf16 fragments ----
  short8 qh[2], kh[2];
#pragma unroll
  for (int j = 0; j < 2; ++j)
#pragma unroll
    for (int e = 0; e < 8; ++e) {
      qh[j][e] = (short)f2bf(qf[j][e]);
      kh[j][e] = (short)f2bf(kf[j][e]);
    }

  // ---- S' = K * Q^T : lane holds S'[t=quad*4+i][h=l16] ----
  f32x4 acc = (f32x4){0.f, 0.f, 0.f, 0.f};
  acc = __builtin_amdgcn_mfma_f32_16x16x32_bf16(kh[0], qh[0], acc, 0, 0, 0);
  acc = __builtin_amdgcn_mfma_f32_16x16x32_bf16(kh[1], qh[1], acc, 0, 0, 0);

  // ---- softmax over t (4 in-lane + cross-quad) ----
  float sc[4];
#pragma unroll
  for (int i = 0; i < 4; ++i) sc[i] = acc[i] * 0.125f;   // 1/sqrt(64)
  float mx = fmaxf(fmaxf(sc[0], sc[1]), fmaxf(sc[2], sc[3]));
  mx = fmaxf(mx, __shfl_xor(mx, 16));
  mx = fmaxf(mx, __shfl_xor(mx, 32));
  float ee[4];
  float sum = 0.f;
#pragma unroll
  for (int i = 0; i < 4; ++i) { ee[i] = expf(sc[i] - mx); sum += ee[i]; }
  sum += __shfl_xor(sum, 16);
  sum += __shfl_xor(sum, 32);
  float inv = 1.0f / sum;
  f32x4 av;
#pragma unroll
  for (int i = 0; i < 4; ++i) av[i] = ee[i] * inv;

  // ---- attn store: attn[m, h=l16, t=quad*4+i], one f32x4 per lane ----
  *(f32x4*)(attn_out + (size_t)m * 256 + l16 * 16 + quad * 4) = av;

  // ---- gather full attn row a[h=l16][t] via shfl ----
  float sh[4][4];
#pragma unroll
  for (int i = 0; i < 4; ++i) {
    sh[0][i] = av[i];
    sh[1][i] = __shfl_xor(av[i], 16);
    sh[2][i] = __shfl_xor(av[i], 32);
    sh[3][i] = __shfl_xor(sh[1][i], 32);
  }

  // ---- PV: ctx[h=l16][d = quad*16 + 0..15] ----
  asm volatile("s_waitcnt vmcnt(0)" ::: "memory");
  float c[16];
#pragma unroll
  for (int d = 0; d < 16; ++d) c[d] = 0.f;
  const unsigned short(*vw)[64] = vs[w];
  int d0 = quad * 16;
#pragma unroll
  for (int qq = 0; qq < 4; ++qq) {
    int tb = ((quad ^ qq) << 2);
#pragma unroll
    for (int i = 0; i < 4; ++i) {
      int t = tb + i;
      float aval = sh[qq][i];
      short8 v0 = *(const short8*)&vw[t][d0];
      short8 v1 = *(const short8*)&vw[t][d0 + 8];
#pragma unroll
      for (int d = 0; d < 8; ++d) {
        c[d]     = fmaf(aval, bf2f((unsigned short)v0[d]), c[d]);
        c[8 + d] = fmaf(aval, bf2f((unsigned short)v1[d]), c[8 + d]);
      }
    }
  }

  // ---- ctx store in transpose(0,2,1,3)-scrambled layout, 2x short8/lane ----
  int row = b * SEQ + l16 * 128 + (s >> 4);
  int col = (s & 15) * 64 + d0;
  unsigned short* cp = ctx_h + (size_t)row * HD + col;
  short8 o0, o1;
#pragma unroll
  for (int d = 0; d < 8; ++d) {
    o0[d] = (short)f2bf(c[d]);
    o1[d] = (short)f2bf(c[8 + d]);
  }
  *(short8*)cp = o0;
  *((short8*)(cp + 8)) = o1;
}

extern "C" void kernel_launch(void* const* d_in, const int* in_sizes, int n_in,
                              void* d_out, int out_size, void* d_ws, size_t ws_size,
                              hipStream_t stream) {
  const float* inputs  = (const float*)d_in[0];
  const float* context = (const float*)d_in[1];
  const float* Wq = (const float*)d_in[2];
  const float* bq = (const float*)d_in[3];
  const float* Wk = (const float*)d_in[4];
  const float* bk = (const float*)d_in[5];
  const float* Wv = (const float*)d_in[6];
  const float* bv = (const float*)d_in[7];
  const float* Wo = (const float*)d_in[8];
  const float* bo = (const float*)d_in[9];

  float* out  = (float*)d_out;                     // [2,2048,1024] flat
  float* attn = out + (size_t)4096 * 1024;         // [2,2048,16,16] flat

  // ws layout (MB offsets): q=0, k=8, v=16, wt=24..32, Ih=32..40, Ch=40..48.
  // ctxh aliases Ih (dead after gemm_qkv; cross-dispatch only).
  const size_t MB = 1ull << 20;
  char* wsb = (char*)d_ws;
  unsigned short* q  = (unsigned short*)(wsb + 0 * MB);
  unsigned short* k  = (unsigned short*)(wsb + 8 * MB);
  unsigned short* v  = (unsigned short*)(wsb + 16 * MB);
  unsigned short* wt = (unsigned short*)(wsb + 24 * MB);
  unsigned short* Ih = (unsigned short*)(wsb + 32 * MB);
  unsigned short* Ch = (unsigned short*)(wsb + 40 * MB);
  unsigned short* ctxh = Ih;   // alias, cross-dispatch only

  prep<<<8192, 256, 0, stream>>>(inputs, context, Wq, Wk, Wv, Wo, Ih, Ch, wt);

  gemm_qkv<<<dim3(32, 8, 3), 256, 0, stream>>>(Ih, Ch, wt, bq, bk, bv, q, k, v);

  attn_rope_k<<<1024, 256, 0, stream>>>(q, k, v, attn, ctxh);

  const size_t P = (size_t)1024 * 1024;
  gemm_o<<<dim3(32, 16), 256, 0, stream>>>(ctxh, wt + 3 * P, bo, out);
}